// Round 1
// baseline (5268.546 us; speedup 1.0000x reference)
//
#include <hip/hip_runtime.h>
#include <cstdint>
#include <cstddef>

#define GLOBAL_AS __attribute__((address_space(1)))
#define LDS_AS    __attribute__((address_space(3)))

typedef _Float16 half2v __attribute__((ext_vector_type(2)));
typedef _Float16 half4v __attribute__((ext_vector_type(4)));
typedef _Float16 half8v __attribute__((ext_vector_type(8)));
typedef float    f32x4  __attribute__((ext_vector_type(4)));

#define T_SEQ 128
#define NBATCH 32
#define HID   1024
#define VOCAB 32000
#define MROWS (T_SEQ * NBATCH)   // 4096

// ---------------------------------------------------------------- utilities

__device__ __forceinline__ void load16_to_lds(const _Float16* gp, _Float16* lp) {
    // async global->LDS, 16B per lane; LDS dest must be wave-uniform base + lane*16
    __builtin_amdgcn_global_load_lds((const GLOBAL_AS uint32_t*)gp,
                                     (LDS_AS uint32_t*)lp, 16, 0, 0);
}

__device__ __forceinline__ float dot2(uint32_t w, uint32_t h, float acc) {
#if __has_builtin(__builtin_amdgcn_fdot2)
    return __builtin_amdgcn_fdot2(__builtin_bit_cast(half2v, w),
                                  __builtin_bit_cast(half2v, h), acc, false);
#else
    half2v a = __builtin_bit_cast(half2v, w);
    half2v b = __builtin_bit_cast(half2v, h);
    return acc + (float)a.x * (float)b.x + (float)a.y * (float)b.y;
#endif
}

__device__ __forceinline__ uint32_t pkh2(float a, float b) {
    half2v h = {(_Float16)a, (_Float16)b};
    return __builtin_bit_cast(uint32_t, h);
}

// ------------------------------------------------------------- conversions

// flat f32 -> f16, 4 elems/thread, grid-stride
__global__ __launch_bounds__(256) void cvt_f32_f16(const float4* __restrict__ src,
                                                   half4v* __restrict__ dst, int n4) {
    int i = blockIdx.x * 256 + threadIdx.x;
    int stride = gridDim.x * 256;
    for (; i < n4; i += stride) {
        float4 v = src[i];
        half4v h = {(_Float16)v.x, (_Float16)v.y, (_Float16)v.z, (_Float16)v.w};
        dst[i] = h;
    }
}

// Pack Wh (per layer [1024(j)][1024(i)]) into whq[l][g][j] : uint4 of 4xhalf2 =
// Wh[j][8g..8g+7]  (i.e. transposed, k-pairs contiguous per column, coalesced over j)
__global__ __launch_bounds__(256) void pack_whT(const float* __restrict__ Wh,
                                                uint4* __restrict__ q) {
    int idx = blockIdx.x * 256 + threadIdx.x;   // 0 .. 2*128*1024-1
    int l   = idx >> 17;
    int rem = idx & 131071;
    int g   = rem >> 10;
    int j   = rem & 1023;
    const float* s = Wh + ((size_t)l << 20) + ((size_t)j << 10) + (g << 3);
    uint4 o;
    o.x = pkh2(s[0], s[1]);
    o.y = pkh2(s[2], s[3]);
    o.z = pkh2(s[4], s[5]);
    o.w = pkh2(s[6], s[7]);
    q[idx] = o;
}

// x_h[r][:] = (f16) emb[ix[r]][:]   r = t*NBATCH+b
__global__ __launch_bounds__(256) void gather_x(const int* __restrict__ ix,
                                                const float4* __restrict__ emb4,
                                                half4v* __restrict__ x4) {
    int r = blockIdx.x;
    int t = threadIdx.x;
    int tok = ix[r];
    float4 v = emb4[(size_t)tok * 256 + t];
    half4v h = {(_Float16)v.x, (_Float16)v.y, (_Float16)v.z, (_Float16)v.w};
    x4[(size_t)r * 256 + t] = h;
}

// ------------------------------------------------------------- f16 MFMA GEMM
// C[M,N] = A[M,K] * B[N,K]^T + bias[N]    (m97 structure: 128x128 tile, BK=32,
// 256 thr = 4 waves each 64x64, global_load_lds 16B staging)
__global__ __launch_bounds__(256) void gemm_f16_bt(const _Float16* __restrict__ A,
                                                   const _Float16* __restrict__ B,
                                                   const float* __restrict__ bias,
                                                   float* __restrict__ C,
                                                   int M, int N, int K) {
    __shared__ __align__(16) _Float16 As[128 * 32];
    __shared__ __align__(16) _Float16 Bs[128 * 32];
    const int t    = threadIdx.x;
    const int lane = t & 63;
    const int wave = t >> 6;
    const int wm   = (wave >> 1) << 6;
    const int wn   = (wave & 1) << 6;
    const int lr   = lane & 15;
    const int quad = lane >> 4;
    const long mBase = (long)blockIdx.y << 7;
    const long nBase = (long)blockIdx.x << 7;

    const int srow = t >> 2;            // 4 threads/row, 16B each (32 f16 per row)
    const int scol = (t & 3) << 3;
    const _Float16* gA0 = A + (mBase + srow) * (long)K + scol;
    const _Float16* gA1 = A + (mBase + srow + 64) * (long)K + scol;
    const _Float16* gB0 = B + (nBase + srow) * (long)K + scol;
    const _Float16* gB1 = B + (nBase + srow + 64) * (long)K + scol;
    _Float16* lA0 = As + t * 8;
    _Float16* lA1 = As + (t + 256) * 8;
    _Float16* lB0 = Bs + t * 8;
    _Float16* lB1 = Bs + (t + 256) * 8;

    f32x4 acc[4][4] = {};

    for (int k0 = 0; k0 < K; k0 += 32) {
        load16_to_lds(gA0 + k0, lA0);
        load16_to_lds(gA1 + k0, lA1);
        load16_to_lds(gB0 + k0, lB0);
        load16_to_lds(gB1 + k0, lB1);
        __syncthreads();   // drains vmcnt before LDS reads

        half8v aF[4], bF[4];
#pragma unroll
        for (int i = 0; i < 4; ++i) {
            aF[i] = *(const half8v*)&As[(wm + i * 16 + lr) * 32 + quad * 8];
            bF[i] = *(const half8v*)&Bs[(wn + i * 16 + lr) * 32 + quad * 8];
        }
#pragma unroll
        for (int mi = 0; mi < 4; ++mi)
#pragma unroll
            for (int ni = 0; ni < 4; ++ni)
                acc[mi][ni] = __builtin_amdgcn_mfma_f32_16x16x32_f16(
                    aF[mi], bF[ni], acc[mi][ni], 0, 0, 0);
        __syncthreads();
    }

    // C/D layout: col = lane&15, row = quad*4 + r   (m89-verified)
#pragma unroll
    for (int ni = 0; ni < 4; ++ni) {
        long col = nBase + wn + ni * 16 + lr;
        float bv = bias ? bias[col] : 0.0f;
#pragma unroll
        for (int mi = 0; mi < 4; ++mi) {
            long row0 = mBase + wm + mi * 16 + quad * 4;
#pragma unroll
            for (int r = 0; r < 4; ++r)
                C[(row0 + r) * (long)N + col] = acc[mi][ni][r] + bv;
        }
    }
}

// ------------------------------------------------------------- RNN recurrence
// One workgroup per batch chain (batches independent -> no inter-WG sync).
// h state as f16 in LDS; Wh^T pre-packed so each thread reads dwordx4 per 8 k.
__global__ __launch_bounds__(256) void rnn_layer(const float* __restrict__ xw,   // [4096,1024]
                                                 const uint4* __restrict__ whq,  // [128][1024]
                                                 const float* __restrict__ bh,   // [1024]
                                                 const float* __restrict__ h0,   // [32,1024]
                                                 _Float16* __restrict__ y,       // [4096,1024]
                                                 float* __restrict__ hT) {       // [32,1024]
    __shared__ __align__(16) _Float16 hh[1024];
    const int b  = blockIdx.x;
    const int t0 = threadIdx.x;
    const int j0 = t0, j1 = t0 + 256, j2 = t0 + 512, j3 = t0 + 768;

    const float bh0 = bh[j0], bh1 = bh[j1], bh2 = bh[j2], bh3 = bh[j3];
    float hl0 = h0[b * 1024 + j0], hl1 = h0[b * 1024 + j1];
    float hl2 = h0[b * 1024 + j2], hl3 = h0[b * 1024 + j3];
    hh[j0] = (_Float16)hl0; hh[j1] = (_Float16)hl1;
    hh[j2] = (_Float16)hl2; hh[j3] = (_Float16)hl3;
    __syncthreads();

    const uint4* w0 = whq + j0;
    const uint4* w1 = whq + j1;
    const uint4* w2 = whq + j2;
    const uint4* w3 = whq + j3;

    for (int t = 0; t < T_SEQ; ++t) {
        const float* xr = xw + ((size_t)(t * NBATCH + b) << 10);
        float a0 = xr[j0] + bh0;
        float a1 = xr[j1] + bh1;
        float a2 = xr[j2] + bh2;
        float a3 = xr[j3] + bh3;
#pragma unroll 2
        for (int g = 0; g < 128; ++g) {
            uint4 hv = *(const uint4*)&hh[g * 8];     // broadcast: 4x half2 of h
            uint4 q0 = w0[g << 10];
            uint4 q1 = w1[g << 10];
            uint4 q2 = w2[g << 10];
            uint4 q3 = w3[g << 10];
            a0 = dot2(q0.x, hv.x, a0); a0 = dot2(q0.y, hv.y, a0);
            a0 = dot2(q0.z, hv.z, a0); a0 = dot2(q0.w, hv.w, a0);
            a1 = dot2(q1.x, hv.x, a1); a1 = dot2(q1.y, hv.y, a1);
            a1 = dot2(q1.z, hv.z, a1); a1 = dot2(q1.w, hv.w, a1);
            a2 = dot2(q2.x, hv.x, a2); a2 = dot2(q2.y, hv.y, a2);
            a2 = dot2(q2.z, hv.z, a2); a2 = dot2(q2.w, hv.w, a2);
            a3 = dot2(q3.x, hv.x, a3); a3 = dot2(q3.y, hv.y, a3);
            a3 = dot2(q3.z, hv.z, a3); a3 = dot2(q3.w, hv.w, a3);
        }
        hl0 = tanhf(a0); hl1 = tanhf(a1); hl2 = tanhf(a2); hl3 = tanhf(a3);
        __syncthreads();                 // everyone done reading hh
        hh[j0] = (_Float16)hl0; hh[j1] = (_Float16)hl1;
        hh[j2] = (_Float16)hl2; hh[j3] = (_Float16)hl3;
        _Float16* yr = y + ((size_t)(t * NBATCH + b) << 10);
        yr[j0] = (_Float16)hl0; yr[j1] = (_Float16)hl1;
        yr[j2] = (_Float16)hl2; yr[j3] = (_Float16)hl3;
        __syncthreads();                 // hh visible for next step
    }
    hT[b * 1024 + j0] = hl0;
    hT[b * 1024 + j1] = hl1;
    hT[b * 1024 + j2] = hl2;
    hT[b * 1024 + j3] = hl3;
}

// ------------------------------------------------------------- log_softmax
// In-place per row of [4096][32000]; 3 passes (max / sumexp / subtract),
// passes 2-3 ride L2 (row = 128 KB just touched).
__global__ __launch_bounds__(256) void logsoftmax_rows(float* __restrict__ logits) {
    const long r = blockIdx.x;
    float4* row = (float4*)(logits + r * (long)VOCAB);   // 8000 float4
    __shared__ float red[256];
    const int t = threadIdx.x;

    float m = -3.4e38f;
    for (int i = t; i < 8000; i += 256) {
        float4 v = row[i];
        m = fmaxf(m, fmaxf(fmaxf(v.x, v.y), fmaxf(v.z, v.w)));
    }
    red[t] = m; __syncthreads();
    for (int o = 128; o > 0; o >>= 1) {
        if (t < o) red[t] = fmaxf(red[t], red[t + o]);
        __syncthreads();
    }
    m = red[0]; __syncthreads();

    float s = 0.0f;
    for (int i = t; i < 8000; i += 256) {
        float4 v = row[i];
        s += __expf(v.x - m) + __expf(v.y - m) + __expf(v.z - m) + __expf(v.w - m);
    }
    red[t] = s; __syncthreads();
    for (int o = 128; o > 0; o >>= 1) {
        if (t < o) red[t] += red[t + o];
        __syncthreads();
    }
    const float lse = m + __logf(red[0]);

    for (int i = t; i < 8000; i += 256) {
        float4 v = row[i];
        v.x -= lse; v.y -= lse; v.z -= lse; v.w -= lse;
        row[i] = v;
    }
}

// ------------------------------------------------------------------- launch

extern "C" void kernel_launch(void* const* d_in, const int* in_sizes, int n_in,
                              void* d_out, int out_size, void* d_ws, size_t ws_size,
                              hipStream_t stream) {
    const int*   ix    = (const int*)  d_in[0];
    const float* hid0  = (const float*)d_in[1];   // [2,32,1024]
    const float* emb   = (const float*)d_in[2];   // [32000,1024]
    const float* W_ih  = (const float*)d_in[3];   // [2,1024,1024]
    const float* W_hh  = (const float*)d_in[4];   // [2,1024,1024]
    const float* b_ih  = (const float*)d_in[5];   // [2,1024]
    const float* b_hh  = (const float*)d_in[6];   // [2,1024]
    const float* W_out = (const float*)d_in[7];   // [32000,1024]
    const float* b_out = (const float*)d_in[8];   // [32000]

    float* logits = (float*)d_out;                       // [4096][32000]
    float* hidT   = logits + (size_t)MROWS * VOCAB;      // [2][32][1024]

    char* ws = (char*)d_ws;
    _Float16* Wi_h   = (_Float16*)ws;  ws += (size_t)2 * 1024 * 1024 * sizeof(_Float16);
    _Float16* Wout_h = (_Float16*)ws;  ws += (size_t)VOCAB * 1024 * sizeof(_Float16);
    uint4*    whq    = (uint4*)ws;     ws += (size_t)2 * 128 * 1024 * sizeof(uint4);
    _Float16* x_h    = (_Float16*)ws;  ws += (size_t)MROWS * 1024 * sizeof(_Float16);
    _Float16* y_h    = (_Float16*)ws;  ws += (size_t)MROWS * 1024 * sizeof(_Float16);
    float*    xw     = (float*)ws;     ws += (size_t)MROWS * 1024 * sizeof(float);

    // weight conversions (every call; required since inputs are restored each run)
    cvt_f32_f16<<<2048, 256, 0, stream>>>((const float4*)W_ih, (half4v*)Wi_h,
                                          2 * 1024 * 1024 / 4);
    cvt_f32_f16<<<8192, 256, 0, stream>>>((const float4*)W_out, (half4v*)Wout_h,
                                          VOCAB * 1024 / 4);
    pack_whT<<<1024, 256, 0, stream>>>(W_hh, whq);
    gather_x<<<MROWS, 256, 0, stream>>>(ix, (const float4*)emb, (half4v*)x_h);

    dim3 g1(HID / 128, MROWS / 128);      // (8, 32)
    // layer 0
    gemm_f16_bt<<<g1, 256, 0, stream>>>(x_h, Wi_h, b_ih, xw, MROWS, HID, HID);
    rnn_layer<<<NBATCH, 256, 0, stream>>>(xw, whq, b_hh, hid0, y_h, hidT);
    // layer 1
    gemm_f16_bt<<<g1, 256, 0, stream>>>(y_h, Wi_h + 1024 * 1024, b_ih + 1024, xw,
                                        MROWS, HID, HID);
    rnn_layer<<<NBATCH, 256, 0, stream>>>(xw, whq + 128 * 1024, b_hh + 1024,
                                          hid0 + 32 * 1024, x_h, hidT + 32 * 1024);
    // output projection + bias
    dim3 g3(VOCAB / 128, MROWS / 128);    // (250, 32)
    gemm_f16_bt<<<g3, 256, 0, stream>>>(x_h, Wout_h, b_out, logits, MROWS, VOCAB, HID);
    // in-place log-softmax
    logsoftmax_rows<<<MROWS, 256, 0, stream>>>(logits);
}